// Round 1
// 280.989 us; speedup vs baseline: 1.1011x; 1.1011x over previous
//
#include <hip/hip_runtime.h>

#define NB 4
#define NH 16
#define SS 2048
#define DD 64
#define QT 128     // query rows per block (32 per wave)
#define KT 64      // keys per tile (two 32-key halves)
#define NT (SS / KT)
#define KSP 72     // ks row stride (bf16)
#define VSP 72     // vsT row stride (bf16)
#define QSCALE 0.18033688011112042f   // (1/8) * log2(e)  -> exp2 domain
#define MASK_BITS_BYTES ((size_t)NB * SS * (SS / 8))   // 2 MiB

typedef __bf16 bf16x8 __attribute__((ext_vector_type(8)));
typedef __bf16 bf16x2 __attribute__((ext_vector_type(2)));
typedef float  floatx16 __attribute__((ext_vector_type(16)));
typedef unsigned long long u64t;

static_assert(sizeof(bf16x8) == 16, "bf16x8 must be 16B");

__device__ __forceinline__ int pack2(float a, float b) {
    bf16x2 v; v[0] = (__bf16)a; v[1] = (__bf16)b;
    return __builtin_bit_cast(int, v);
}

// ---- pre-pass: pack mask int32 [B,S,S] -> bits, bit j of ull w = key 64w+j ----
// 2048 fat blocks (32 ballots per wave) instead of 65536 tiny ones: the old
// launch was workgroup-dispatch-overhead bound.
__global__ __launch_bounds__(256)
void pack_mask_kernel(const int* __restrict__ M, u64t* __restrict__ bits)
{
    const int w    = (blockIdx.x * 256 + threadIdx.x) >> 6;  // 0..8191
    const int lane = threadIdx.x & 63;
    #pragma unroll 4
    for (int i = 0; i < 32; ++i) {
        const int gw   = i * 8192 + w;                // contiguous across waves
        const size_t row = (size_t)(gw >> 5);
        const int word = gw & 31;
        const int mval = M[row * SS + (size_t)word * 64 + lane];
        const u64t b = __ballot(mval == 1);
        if (lane == 0) bits[gw] = b;
    }
}

template<bool USE_BITS>
__global__ __launch_bounds__(256, 4)
void attn_kernel(const float* __restrict__ Q, const float* __restrict__ K,
                 const float* __restrict__ V, const int* __restrict__ M,
                 const unsigned* __restrict__ MB, float* __restrict__ O)
{
    // double-buffered K / V^T tiles, single barrier per tile
    __shared__ __bf16 ks [2][KT][KSP];    // [buf][key][dim]
    __shared__ __bf16 vsT[2][DD][VSP];    // [buf][dim][perm-key-col]

    const int t    = threadIdx.x;
    const int wave = t >> 6;
    const int lane = t & 63;
    const int l31  = lane & 31;
    const int h8   = lane >> 5;

    // XCD-affinity decode: all 16 q-tiles of a head share blockIdx%8 -> one XCD L2
    const int bh    = blockIdx.x & 63;
    const int qtile = blockIdx.x >> 6;
    const int b     = bh >> 4;
    const int q0    = qtile * QT + wave * 32;

    const size_t base = (size_t)bh * SS * DD;
    const float* Qb = Q + base;
    const float* Kb = K + base;
    const float* Vb = V + base;

    // ---- persistent Q B-fragments: B[k=16s+8h8+j][n=q=l31], exp2 domain ----
    bf16x8 aq[4];
    {
        const float* qp = Qb + (size_t)(q0 + l31) * DD + 8 * h8;
        #pragma unroll
        for (int s = 0; s < 4; ++s) {
            float4 f0 = *(const float4*)(qp + 16 * s);
            float4 f1 = *(const float4*)(qp + 16 * s + 4);
            bf16x8 a;
            a[0] = (__bf16)(f0.x * QSCALE); a[1] = (__bf16)(f0.y * QSCALE);
            a[2] = (__bf16)(f0.z * QSCALE); a[3] = (__bf16)(f0.w * QSCALE);
            a[4] = (__bf16)(f1.x * QSCALE); a[5] = (__bf16)(f1.y * QSCALE);
            a[6] = (__bf16)(f1.z * QSCALE); a[7] = (__bf16)(f1.w * QSCALE);
            aq[s] = a;
        }
    }

    // staging assignments (256 threads; 64x64 K tile, 64x64 V tile)
    const int skey = t >> 3;            // K: keys skey, skey+32
    const int sdc  = (t & 7) * 8;       // K: 8 dims
    const int vk   = 2 * (t & 15);      // V: keys vk, vk+1 (+32, +33)
    const int vdc  = (t >> 4) * 4;      // V: 4 dims
    // permuted column so QK C-regs are the PV B-fragment verbatim
    const int vcol = 16 * (vk >> 4) + 8 * ((vk >> 2) & 1) + (vk & 3) + 4 * ((vk >> 3) & 1);

    const float* kp0 = Kb + (size_t)skey * DD + sdc;
    const float* vp0 = Vb + (size_t)vk * DD + vdc;

    // prologue: prefetch tile 0 (8 float4 in flight)
    float4 ka0 = ((const float4*)kp0)[0];
    float4 ka1 = ((const float4*)kp0)[1];
    float4 kb0 = ((const float4*)(kp0 + 32 * DD))[0];
    float4 kb1 = ((const float4*)(kp0 + 32 * DD))[1];
    float4 va0 = *(const float4*)(vp0);
    float4 va1 = *(const float4*)(vp0 + DD);
    float4 vb0 = *(const float4*)(vp0 + 32 * DD);
    float4 vb1 = *(const float4*)(vp0 + 33 * DD);

    // mask pointers for row (q0 + l31)
    const u64t* mbrow = (const u64t*)MB + ((size_t)b * SS + q0 + l31) * (SS / 64);
    const int*  mrow  = M + (size_t)b * SS * SS + (size_t)(q0 + l31) * SS + 4 * h8;

    floatx16 o0, o1;
    #pragma unroll
    for (int i = 0; i < 16; ++i) { o0[i] = 0.f; o1[i] = 0.f; }
    float ls = 0.f;

    for (int tt = 0; tt < NT; ++tt) {
        const int cur = tt & 1;

        // ---- stage tile tt: regs -> LDS buf[cur] (K natural, V transposed+permuted)
        // safe: all waves passed previous sync => consumers of buf[cur] (tt-2) done
        {
            bf16x8 kw;
            kw[0]=(__bf16)ka0.x; kw[1]=(__bf16)ka0.y; kw[2]=(__bf16)ka0.z; kw[3]=(__bf16)ka0.w;
            kw[4]=(__bf16)ka1.x; kw[5]=(__bf16)ka1.y; kw[6]=(__bf16)ka1.z; kw[7]=(__bf16)ka1.w;
            *(bf16x8*)&ks[cur][skey][sdc] = kw;
            kw[0]=(__bf16)kb0.x; kw[1]=(__bf16)kb0.y; kw[2]=(__bf16)kb0.z; kw[3]=(__bf16)kb0.w;
            kw[4]=(__bf16)kb1.x; kw[5]=(__bf16)kb1.y; kw[6]=(__bf16)kb1.z; kw[7]=(__bf16)kb1.w;
            *(bf16x8*)&ks[cur][skey + 32][sdc] = kw;
            #pragma unroll
            for (int i = 0; i < 4; ++i) {
                bf16x2 pr;
                pr[0] = (__bf16)(&va0.x)[i]; pr[1] = (__bf16)(&va1.x)[i];
                *(bf16x2*)&vsT[cur][vdc + i][vcol] = pr;
                pr[0] = (__bf16)(&vb0.x)[i]; pr[1] = (__bf16)(&vb1.x)[i];
                *(bf16x2*)&vsT[cur][vdc + i][32 + vcol] = pr;
            }
        }
        __syncthreads();   // publish buf[cur]; nothing outstanding in vmcnt here

        // ---- mask fetch for current tile (one 8B load on bits path) ----
        u64t mall = 0;
        int4 mi[8];
        if (USE_BITS) {
            mall = mbrow[tt];
        } else {
            #pragma unroll
            for (int g = 0; g < 8; ++g)
                mi[g] = *(const int4*)(mrow + tt * KT + 8 * g);
        }

        // ---- prefetch next K/V tile; consumed by staging BEFORE next barrier,
        //      so these never force a vmcnt(0) drain at a barrier ----
        {
            const int jn = ((tt + 1) * KT) & (SS - 1);
            const float* kn = kp0 + (size_t)jn * DD;
            ka0 = ((const float4*)kn)[0];
            ka1 = ((const float4*)kn)[1];
            kb0 = ((const float4*)(kn + 32 * DD))[0];
            kb1 = ((const float4*)(kn + 32 * DD))[1];
            const float* vn = vp0 + (size_t)jn * DD;
            va0 = *(const float4*)(vn);
            va1 = *(const float4*)(vn + DD);
            vb0 = *(const float4*)(vn + 32 * DD);
            vb1 = *(const float4*)(vn + 33 * DD);
        }

        // ---- compute: two 32-key halves, 16 MFMA each ----
        #pragma unroll
        for (int half = 0; half < 2; ++half) {
            // S^T = K·Q^T : C[m=key][n=q=l31], key=(i&3)+8(i>>2)+4h8 (+32*half)
            floatx16 c;
            #pragma unroll
            for (int i = 0; i < 16; ++i) c[i] = 0.f;
            __builtin_amdgcn_s_setprio(1);
            #pragma unroll
            for (int s = 0; s < 4; ++s) {
                bf16x8 a = *(const bf16x8*)&ks[cur][32 * half + l31][16 * s + 8 * h8];
                c = __builtin_amdgcn_mfma_f32_32x32x16_bf16(a, aq[s], c, 0, 0, 0);
            }
            __builtin_amdgcn_s_setprio(0);

            // p = exp2(c), mask -> 0 (no max shift: scores bounded)
            const unsigned mw = USE_BITS ? (unsigned)(mall >> (32 * half)) : 0u;
            const unsigned u  = mw >> (4 * h8);
            int pk[8];
            float psum = 0.f;
            #pragma unroll
            for (int g = 0; g < 8; ++g) {
                const int ia = 2 * g, ib = 2 * g + 1;
                float pa = __builtin_amdgcn_exp2f(c[ia]);
                float pb = __builtin_amdgcn_exp2f(c[ib]);
                bool ma, mb_;
                if (USE_BITS) {
                    ma  = (u >> ((ia & 3) + 8 * (ia >> 2))) & 1;
                    mb_ = (u >> ((ib & 3) + 8 * (ib >> 2))) & 1;
                } else {
                    const int g2 = 4 * half + (ia >> 2);
                    ma  = ((&mi[g2].x)[ia & 3] == 1);
                    mb_ = ((&mi[g2].x)[ib & 3] == 1);
                }
                pa = ma  ? 0.f : pa;
                pb = mb_ ? 0.f : pb;
                psum += pa + pb;
                pk[g] = pack2(pa, pb);
            }
            ls += psum;

            // PV: O^T += V^T(perm) · P^T ; bp = c-regs packed verbatim
            __builtin_amdgcn_s_setprio(1);
            #pragma unroll
            for (int s2 = 0; s2 < 2; ++s2) {
                int4 fw; fw.x = pk[4*s2]; fw.y = pk[4*s2+1]; fw.z = pk[4*s2+2]; fw.w = pk[4*s2+3];
                bf16x8 bp = __builtin_bit_cast(bf16x8, fw);
                bf16x8 av0 = *(const bf16x8*)&vsT[cur][l31][32 * half + 16 * s2 + 8 * h8];
                bf16x8 av1 = *(const bf16x8*)&vsT[cur][32 + l31][32 * half + 16 * s2 + 8 * h8];
                o0 = __builtin_amdgcn_mfma_f32_32x32x16_bf16(av0, bp, o0, 0, 0, 0);
                o1 = __builtin_amdgcn_mfma_f32_32x32x16_bf16(av1, bp, o1, 0, 0, 0);
            }
            __builtin_amdgcn_s_setprio(0);
        }
    }

    // ---- epilogue ----
    ls += __shfl_xor(ls, 32);        // other half-lane holds the other 16 keys/row
    float inv = 1.0f / ls;
    float* op = O + base + (size_t)(q0 + l31) * DD;
    #pragma unroll
    for (int s = 0; s < 4; ++s) {
        float4 st0, st1;
        st0.x = o0[4*s+0] * inv; st0.y = o0[4*s+1] * inv;
        st0.z = o0[4*s+2] * inv; st0.w = o0[4*s+3] * inv;
        st1.x = o1[4*s+0] * inv; st1.y = o1[4*s+1] * inv;
        st1.z = o1[4*s+2] * inv; st1.w = o1[4*s+3] * inv;
        *(float4*)(op + 8 * s + 4 * h8)      = st0;
        *(float4*)(op + 32 + 8 * s + 4 * h8) = st1;
    }
}

extern "C" void kernel_launch(void* const* d_in, const int* in_sizes, int n_in,
                              void* d_out, int out_size, void* d_ws, size_t ws_size,
                              hipStream_t stream) {
    (void)in_sizes; (void)n_in; (void)out_size;
    const float* q = (const float*)d_in[0];
    const float* k = (const float*)d_in[1];
    const float* v = (const float*)d_in[2];
    const int*   m = (const int*)d_in[3];
    float* out = (float*)d_out;
    dim3 grid(NB * NH * (SS / QT));   // 1024 blocks = 4 per CU

    if (ws_size >= MASK_BITS_BYTES) {
        u64t* bits = (u64t*)d_ws;
        pack_mask_kernel<<<dim3(2048), 256, 0, stream>>>(m, bits);
        attn_kernel<true><<<grid, 256, 0, stream>>>(q, k, v, m, (const unsigned*)bits, out);
    } else {
        attn_kernel<false><<<grid, 256, 0, stream>>>(q, k, v, m, (const unsigned*)nullptr, out);
    }
}

// Round 2
// 261.065 us; speedup vs baseline: 1.1851x; 1.0763x over previous
//
#include <hip/hip_runtime.h>

#define NB 4
#define NH 16
#define SS 2048
#define DD 64
#define QT 256     // query rows per block (32 per wave, 8 waves)
#define KT 64      // keys per tile (two 32-key halves)
#define NT (SS / KT)
#define QSCALE 0.18033688011112042f   // (1/8) * log2(e)  -> exp2 domain
#define MASK_BITS_BYTES ((size_t)NB * SS * (SS / 8))   // 2 MiB

typedef __bf16 bf16x8 __attribute__((ext_vector_type(8)));
typedef __bf16 bf16x2 __attribute__((ext_vector_type(2)));
typedef float  floatx16 __attribute__((ext_vector_type(16)));
typedef unsigned long long u64t;

static_assert(sizeof(bf16x8) == 16, "bf16x8 must be 16B");

__device__ __forceinline__ int pack2(float a, float b) {
    bf16x2 v; v[0] = (__bf16)a; v[1] = (__bf16)b;
    return __builtin_bit_cast(int, v);
}

// ---- pre-pass: pack mask int32 [B,S,S] -> bits, bit j of ull w = key 64w+j ----
__global__ __launch_bounds__(256)
void pack_mask_kernel(const int* __restrict__ M, u64t* __restrict__ bits)
{
    const int w    = (blockIdx.x * 256 + threadIdx.x) >> 6;  // 0..8191
    const int lane = threadIdx.x & 63;
    #pragma unroll 4
    for (int i = 0; i < 32; ++i) {
        const int gw   = i * 8192 + w;                // contiguous across waves
        const size_t row = (size_t)(gw >> 5);
        const int word = gw & 31;
        const int mval = M[row * SS + (size_t)word * 64 + lane];
        const u64t b = __ballot(mval == 1);
        if (lane == 0) bits[gw] = b;
    }
}

template<bool USE_BITS>
__global__ __launch_bounds__(512, 4)
void attn_kernel(const float* __restrict__ Q, const float* __restrict__ K,
                 const float* __restrict__ V, const int* __restrict__ M,
                 const unsigned* __restrict__ MB, float* __restrict__ O)
{
    // double-buffered K / V^T tiles, XOR-swizzled (no pad), 32 KiB total
    __shared__ __bf16 ks [2][KT][DD];    // [buf][key][dim], byte ^= (key&7)<<4
    __shared__ __bf16 vsT[2][DD][KT];    // [buf][dim][perm-key], byte ^= (dim&7)<<4

    const int t    = threadIdx.x;
    const int wave = t >> 6;
    const int lane = t & 63;
    const int l31  = lane & 31;
    const int h8   = lane >> 5;

    // XCD-affinity decode: all 8 q-tiles of a head share blockIdx%8 -> one XCD L2
    const int bh    = blockIdx.x & 63;
    const int qtile = blockIdx.x >> 6;
    const int b     = bh >> 4;
    const int q0    = qtile * QT + wave * 32;

    const size_t base = (size_t)bh * SS * DD;
    const float* Qb = Q + base;
    const float* Kb = K + base;
    const float* Vb = V + base;

    // ---- persistent Q B-fragments: B[k=16s+8h8+j][n=q=l31], exp2 domain ----
    bf16x8 aq[4];
    {
        const float* qp = Qb + (size_t)(q0 + l31) * DD + 8 * h8;
        #pragma unroll
        for (int s = 0; s < 4; ++s) {
            float4 f0 = *(const float4*)(qp + 16 * s);
            float4 f1 = *(const float4*)(qp + 16 * s + 4);
            bf16x8 a;
            a[0] = (__bf16)(f0.x * QSCALE); a[1] = (__bf16)(f0.y * QSCALE);
            a[2] = (__bf16)(f0.z * QSCALE); a[3] = (__bf16)(f0.w * QSCALE);
            a[4] = (__bf16)(f1.x * QSCALE); a[5] = (__bf16)(f1.y * QSCALE);
            a[6] = (__bf16)(f1.z * QSCALE); a[7] = (__bf16)(f1.w * QSCALE);
            aq[s] = a;
        }
    }

    // staging assignments (512 threads; 64x64 K tile, 64x64 V tile)
    const int skey = t >> 3;            // K: key 0..63
    const int sdc  = (t & 7) * 8;       // K: 8 dims
    const int vk   = 2 * (t & 31);      // V: keys vk, vk+1 (even, 0..62)
    const int vdc  = (t >> 5) * 4;      // V: 4 dims
    // permuted column so QK C-regs are the PV B-fragment verbatim
    const int vcol = 16 * (vk >> 4) + 8 * ((vk >> 2) & 1) + (vk & 3) + 4 * ((vk >> 3) & 1);

    const float* kp0 = Kb + (size_t)skey * DD + sdc;
    const float* vp0 = Vb + (size_t)vk * DD + vdc;

    // prologue: prefetch tile 0 (4 float4 in flight)
    float4 ka0 = ((const float4*)kp0)[0];
    float4 ka1 = ((const float4*)kp0)[1];
    float4 va0 = *(const float4*)(vp0);
    float4 va1 = *(const float4*)(vp0 + DD);

    // mask pointers for row (q0 + l31)
    const u64t* mbrow = (const u64t*)MB + ((size_t)b * SS + q0 + l31) * (SS / 64);
    const int*  mrow  = M + (size_t)b * SS * SS + (size_t)(q0 + l31) * SS + 4 * h8;

    floatx16 o0, o1;
    #pragma unroll
    for (int i = 0; i < 16; ++i) { o0[i] = 0.f; o1[i] = 0.f; }
    float ls = 0.f;

    for (int tt = 0; tt < NT; ++tt) {
        const int cur = tt & 1;
        char* kb = (char*)&ks[cur][0][0];
        char* vb = (char*)&vsT[cur][0][0];

        // ---- stage tile tt: regs -> LDS buf[cur] (K natural, V transposed+permuted)
        {
            bf16x8 kw;
            kw[0]=(__bf16)ka0.x; kw[1]=(__bf16)ka0.y; kw[2]=(__bf16)ka0.z; kw[3]=(__bf16)ka0.w;
            kw[4]=(__bf16)ka1.x; kw[5]=(__bf16)ka1.y; kw[6]=(__bf16)ka1.z; kw[7]=(__bf16)ka1.w;
            *(bf16x8*)(kb + skey * 128 + ((16 * (t & 7)) ^ ((skey & 7) << 4))) = kw;
            #pragma unroll
            for (int i = 0; i < 4; ++i) {
                bf16x2 pr;
                pr[0] = (__bf16)(&va0.x)[i]; pr[1] = (__bf16)(&va1.x)[i];
                const int dim = vdc + i;
                *(bf16x2*)(vb + dim * 128 + ((2 * vcol) ^ ((dim & 7) << 4))) = pr;
            }
        }
        __syncthreads();   // publish buf[cur]; nothing outstanding in vmcnt here

        // ---- mask fetch for current tile (one 8B load on bits path) ----
        u64t mall = 0;
        int4 mi[8];
        if (USE_BITS) {
            mall = mbrow[tt];
        } else {
            #pragma unroll
            for (int g = 0; g < 8; ++g)
                mi[g] = *(const int4*)(mrow + tt * KT + 8 * g);
        }

        // ---- prefetch next K/V tile; consumed by staging BEFORE next barrier ----
        {
            const int jn = ((tt + 1) * KT) & (SS - 1);
            const float* kn = kp0 + (size_t)jn * DD;
            ka0 = ((const float4*)kn)[0];
            ka1 = ((const float4*)kn)[1];
            const float* vn = vp0 + (size_t)jn * DD;
            va0 = *(const float4*)(vn);
            va1 = *(const float4*)(vn + DD);
        }

        // ---- compute: two 32-key halves, 16 MFMA each ----
        #pragma unroll
        for (int half = 0; half < 2; ++half) {
            // S^T = K·Q^T : C[m=key][n=q=l31], key=(i&3)+8(i>>2)+4h8 (+32*half)
            floatx16 c;
            #pragma unroll
            for (int i = 0; i < 16; ++i) c[i] = 0.f;
            __builtin_amdgcn_s_setprio(1);
            #pragma unroll
            for (int s = 0; s < 4; ++s) {
                const int r = 32 * half + l31;
                bf16x8 a = *(const bf16x8*)(kb + r * 128 +
                              ((32 * s + 16 * h8) ^ ((r & 7) << 4)));
                c = __builtin_amdgcn_mfma_f32_32x32x16_bf16(a, aq[s], c, 0, 0, 0);
            }
            __builtin_amdgcn_s_setprio(0);

            // p = exp2(c), mask -> 0 (no max shift: scores bounded)
            const unsigned mw = USE_BITS ? (unsigned)(mall >> (32 * half)) : 0u;
            const unsigned u  = mw >> (4 * h8);
            int pk[8];
            float psum = 0.f;
            #pragma unroll
            for (int g = 0; g < 8; ++g) {
                const int ia = 2 * g, ib = 2 * g + 1;
                float pa = __builtin_amdgcn_exp2f(c[ia]);
                float pb = __builtin_amdgcn_exp2f(c[ib]);
                bool ma, mb_;
                if (USE_BITS) {
                    ma  = (u >> ((ia & 3) + 8 * (ia >> 2))) & 1;
                    mb_ = (u >> ((ib & 3) + 8 * (ib >> 2))) & 1;
                } else {
                    const int g2 = 4 * half + (ia >> 2);
                    ma  = ((&mi[g2].x)[ia & 3] == 1);
                    mb_ = ((&mi[g2].x)[ib & 3] == 1);
                }
                pa = ma  ? 0.f : pa;
                pb = mb_ ? 0.f : pb;
                psum += pa + pb;
                pk[g] = pack2(pa, pb);
            }
            ls += psum;

            // PV: O^T += V^T(perm) · P^T ; bp = c-regs packed verbatim
            __builtin_amdgcn_s_setprio(1);
            #pragma unroll
            for (int s2 = 0; s2 < 2; ++s2) {
                int4 fw; fw.x = pk[4*s2]; fw.y = pk[4*s2+1]; fw.z = pk[4*s2+2]; fw.w = pk[4*s2+3];
                bf16x8 bp = __builtin_bit_cast(bf16x8, fw);
                const int c2 = 64 * half + 32 * s2 + 16 * h8;
                bf16x8 av0 = *(const bf16x8*)(vb + l31 * 128 +
                               (c2 ^ ((l31 & 7) << 4)));
                bf16x8 av1 = *(const bf16x8*)(vb + (32 + l31) * 128 +
                               (c2 ^ ((l31 & 7) << 4)));
                o0 = __builtin_amdgcn_mfma_f32_32x32x16_bf16(av0, bp, o0, 0, 0, 0);
                o1 = __builtin_amdgcn_mfma_f32_32x32x16_bf16(av1, bp, o1, 0, 0, 0);
            }
            __builtin_amdgcn_s_setprio(0);
        }
    }

    // ---- epilogue ----
    ls += __shfl_xor(ls, 32);        // other half-lane holds the other 16 keys/row
    float inv = 1.0f / ls;
    float* op = O + base + (size_t)(q0 + l31) * DD;
    #pragma unroll
    for (int s = 0; s < 4; ++s) {
        float4 st0, st1;
        st0.x = o0[4*s+0] * inv; st0.y = o0[4*s+1] * inv;
        st0.z = o0[4*s+2] * inv; st0.w = o0[4*s+3] * inv;
        st1.x = o1[4*s+0] * inv; st1.y = o1[4*s+1] * inv;
        st1.z = o1[4*s+2] * inv; st1.w = o1[4*s+3] * inv;
        *(float4*)(op + 8 * s + 4 * h8)      = st0;
        *(float4*)(op + 32 + 8 * s + 4 * h8) = st1;
    }
}

extern "C" void kernel_launch(void* const* d_in, const int* in_sizes, int n_in,
                              void* d_out, int out_size, void* d_ws, size_t ws_size,
                              hipStream_t stream) {
    (void)in_sizes; (void)n_in; (void)out_size;
    const float* q = (const float*)d_in[0];
    const float* k = (const float*)d_in[1];
    const float* v = (const float*)d_in[2];
    const int*   m = (const int*)d_in[3];
    float* out = (float*)d_out;
    dim3 grid(NB * NH * (SS / QT));   // 512 blocks = 2 per CU

    if (ws_size >= MASK_BITS_BYTES) {
        u64t* bits = (u64t*)d_ws;
        pack_mask_kernel<<<dim3(2048), 256, 0, stream>>>(m, bits);
        attn_kernel<true><<<grid, 512, 0, stream>>>(q, k, v, m, (const unsigned*)bits, out);
    } else {
        attn_kernel<false><<<grid, 512, 0, stream>>>(q, k, v, m, (const unsigned*)nullptr, out);
    }
}